// Round 3
// baseline (18830.896 us; speedup 1.0000x reference)
//
#include <hip/hip_runtime.h>
#include <math.h>

// Problem dims (fixed by setup_inputs)
#define B_ROWS 65536
#define DDIM   512
#define NG     4
#define NK     1024
#define NH     128
#define NA     7

// Tiling
#define BM       32          // rows per block
#define NTHREADS 512         // 8 waves
#define TR       4           // rows per thread (wave = rowgroup, 8 waves x 4 rows)
#define TC       4           // codewords per lane per chunk
#define CHUNK    256         // 64 lanes * TC
#define NCHUNK   (NK / CHUNK)
#define KSPLIT   384         // OpenBLAS sgemm K-blocking (GEMM_Q, Zen/Haswell)

#define LDS_BYTES (BM * DDIM * 4 + BM * NH * 4)  // 65536 + 16384 = 81920

// ---------------------------------------------------------------------------
// 0.5 * ||c||^2 emulating numpy fp32 np.sum(C*C, axis=-1):
// pairwise_sum, AVX512 SIMD variant (vstep=16, PW_BLOCKSIZE=128):
//   512 -> 256+256 -> four 128-blocks.
//   128-block: r_j[l] = (x[16j+l]^2 + x[16j+l+64]^2), s[l]=(r0+r1)+(r2+r3),
//   horizontal fold 16->8->4->2->1 by halves.
// One thread per codeword. fp contract OFF: each square must round before add.
// ---------------------------------------------------------------------------
__global__ void rvq_norms_np(const float* __restrict__ cb,
                             float* __restrict__ halfnorm) {
#pragma clang fp contract(off)
    int k = blockIdx.x * blockDim.x + threadIdx.x;
    if (k >= NG * NK) return;
    const float* c = cb + (size_t)k * DDIM;
    float blk[4];
#pragma unroll
    for (int b = 0; b < 4; ++b) {
        const float* p = c + b * 128;
        float s[16];
#pragma unroll
        for (int l = 0; l < 16; ++l) {
            float x0 = p[l],      x1 = p[l + 16], x2 = p[l + 32], x3 = p[l + 48];
            float x4 = p[l + 64], x5 = p[l + 80], x6 = p[l + 96], x7 = p[l + 112];
            float pa = x0 * x0 + x4 * x4;   // pair(l)
            float pb = x1 * x1 + x5 * x5;   // pair(l+16)
            float pc = x2 * x2 + x6 * x6;   // pair(l+32)
            float pd = x3 * x3 + x7 * x7;   // pair(l+48)
            s[l] = (pa + pb) + (pc + pd);
        }
        float h[8];
#pragma unroll
        for (int l = 0; l < 8; ++l) h[l] = s[l] + s[l + 8];
        float q[4];
#pragma unroll
        for (int l = 0; l < 4; ++l) q[l] = h[l] + h[l + 4];
        float r0 = q[0] + q[2];
        float r1 = q[1] + q[3];
        blk[b] = r0 + r1;
    }
    float total = (blk[0] + blk[1]) + (blk[2] + blk[3]);
    halfnorm[k] = 0.5f * total;
}

// ---------------------------------------------------------------------------
// Fused: residual VQ (4 stages, numpy-fp32-emulated scoring) + reference-order
// quantized sum + straight-through + MLP (512->128->128->7).
// Dot product per (row, codeword): sequential ascending-k fp32 FMA with a
// single accumulator per K-block, blocks split at k=384 (OpenBLAS GEMM_Q),
// combined fl(fl(S1)+S2), then one fp32 subtract of 0.5||c||^2.
// ---------------------------------------------------------------------------
__global__ __launch_bounds__(NTHREADS, 2) void rvq_mlp_fused(
    const float* __restrict__ z, const float* __restrict__ cb,
    const float* __restrict__ halfnorm,
    const float* __restrict__ w1, const float* __restrict__ b1,
    const float* __restrict__ w2, const float* __restrict__ b2,
    const float* __restrict__ w3, const float* __restrict__ b3,
    float* __restrict__ out) {
    extern __shared__ char smem[];
    float* resid = (float*)smem;                       // [BM][DDIM]
    float* h1    = (float*)(smem + BM * DDIM * 4);     // [BM][NH]
    int*   idx_s = (int*)(smem + BM * DDIM * 4);       // [NG][BM], aliases h1

    const int tid = threadIdx.x;
    const size_t row0 = (size_t)blockIdx.x * BM;

    // ---- 1) load z tile into LDS ----
    {
        const float4* src = (const float4*)(z + row0 * DDIM);
        float4* dst = (float4*)resid;
#pragma unroll
        for (int i = 0; i < (BM * DDIM / 4) / NTHREADS; ++i)
            dst[tid + i * NTHREADS] = src[tid + i * NTHREADS];
    }
    __syncthreads();

    const int cg = tid & 63;   // lane within wave
    const int rg = tid >> 6;   // wave id (0..7)
    const int r0 = rg * TR;

    // ---- 2) residual VQ stages: np-fp32-emulated argmax ----
    for (int g = 0; g < NG; ++g) {
        const float* C  = cb + (size_t)g * NK * DDIM;
        const float* hn = halfnorm + g * NK;

        float sb[TR];
        int   ib[TR];
#pragma unroll
        for (int r = 0; r < TR; ++r) { sb[r] = -3.4e38f; ib[r] = 0; }

        for (int ch = 0; ch < NCHUNK; ++ch) {
            const int cbase = ch * CHUNK;
            float accA[TR][TC], accB[TR][TC];
#pragma unroll
            for (int r = 0; r < TR; ++r)
#pragma unroll
                for (int j = 0; j < TC; ++j) { accA[r][j] = 0.f; accB[r][j] = 0.f; }

            const float* Cb = C + (size_t)(cbase + cg) * DDIM;
            // K-block 1: k = 0..383, sequential ascending fp32 FMA
            for (int d = 0; d < KSPLIT; d += 4) {
                float4 a[TR];
#pragma unroll
                for (int r = 0; r < TR; ++r)
                    a[r] = *(const float4*)&resid[(r0 + r) * DDIM + d];
#pragma unroll
                for (int j = 0; j < TC; ++j) {
                    float4 cv = *(const float4*)&Cb[(size_t)j * 64 * DDIM + d];
#pragma unroll
                    for (int r = 0; r < TR; ++r) {
                        accA[r][j] = fmaf(a[r].x, cv.x, accA[r][j]);
                        accA[r][j] = fmaf(a[r].y, cv.y, accA[r][j]);
                        accA[r][j] = fmaf(a[r].z, cv.z, accA[r][j]);
                        accA[r][j] = fmaf(a[r].w, cv.w, accA[r][j]);
                    }
                }
            }
            // K-block 2: k = 384..511
            for (int d = KSPLIT; d < DDIM; d += 4) {
                float4 a[TR];
#pragma unroll
                for (int r = 0; r < TR; ++r)
                    a[r] = *(const float4*)&resid[(r0 + r) * DDIM + d];
#pragma unroll
                for (int j = 0; j < TC; ++j) {
                    float4 cv = *(const float4*)&Cb[(size_t)j * 64 * DDIM + d];
#pragma unroll
                    for (int r = 0; r < TR; ++r) {
                        accB[r][j] = fmaf(a[r].x, cv.x, accB[r][j]);
                        accB[r][j] = fmaf(a[r].y, cv.y, accB[r][j]);
                        accB[r][j] = fmaf(a[r].z, cv.z, accB[r][j]);
                        accB[r][j] = fmaf(a[r].w, cv.w, accB[r][j]);
                    }
                }
            }
            // score = fl(fl(S1)+S2) - hn, running argmax (ascending cod per
            // lane -> strict > keeps first occurrence)
#pragma unroll
            for (int j = 0; j < TC; ++j) {
                const int cod = cbase + j * 64 + cg;
                const float hnv = hn[cod];
#pragma unroll
                for (int r = 0; r < TR; ++r) {
                    float dot = accA[r][j] + accB[r][j];
                    float s = dot - hnv;
                    if (s > sb[r]) { sb[r] = s; ib[r] = cod; }
                }
            }
        }

        // ---- butterfly argmax reduce (ties -> lower index) ----
#pragma unroll
        for (int m = 32; m >= 1; m >>= 1) {
#pragma unroll
            for (int r = 0; r < TR; ++r) {
                float os = __shfl_xor(sb[r], m, 64);
                int   oi = __shfl_xor(ib[r], m, 64);
                if (os > sb[r] || (os == sb[r] && oi < ib[r])) {
                    sb[r] = os; ib[r] = oi;
                }
            }
        }
#pragma unroll
        for (int r = 0; r < TR; ++r)
            if (cg == 0) idx_s[g * BM + r0 + r] = ib[r];
        __syncthreads();

        // ---- residual -= chosen codeword (exact fp32, matches reference);
        //      resid after the last stage is never used -> skip ----
        if (g < NG - 1) {
            const int row = tid >> 4;   // 0..31
            const int sub = tid & 15;   // 0..15
            const float4* crow =
                (const float4*)(C + (size_t)idx_s[g * BM + row] * DDIM);
            float4* rrow = (float4*)&resid[row * DDIM];
#pragma unroll
            for (int k = 0; k < 8; ++k) {
                int p = sub + k * 16;
                float4 rv = rrow[p], cv = crow[p];
                rv.x -= cv.x; rv.y -= cv.y; rv.z -= cv.z; rv.w -= cv.w;
                rrow[p] = rv;
            }
            __syncthreads();
        }
    }

    // ---- 3) st = z + (zq - z), zq built in reference fp32 order
    //         (((0+q0)+q1)+q2)+q3; overwrite resid with st ----
    {
        const int row = tid >> 4;
        const int sub = tid & 15;
        const float4* zrow = (const float4*)(z + (row0 + row) * DDIM);
        float4* rrow = (float4*)&resid[row * DDIM];
        const float4* c0 = (const float4*)(cb + ((size_t)0 * NK + idx_s[0 * BM + row]) * DDIM);
        const float4* c1 = (const float4*)(cb + ((size_t)1 * NK + idx_s[1 * BM + row]) * DDIM);
        const float4* c2 = (const float4*)(cb + ((size_t)2 * NK + idx_s[2 * BM + row]) * DDIM);
        const float4* c3 = (const float4*)(cb + ((size_t)3 * NK + idx_s[3 * BM + row]) * DDIM);
#pragma unroll
        for (int k = 0; k < 8; ++k) {
            int p = sub + k * 16;
            float4 q0 = c0[p], q1 = c1[p], q2 = c2[p], q3 = c3[p];
            float4 q;
            q.x = ((q0.x + q1.x) + q2.x) + q3.x;
            q.y = ((q0.y + q1.y) + q2.y) + q3.y;
            q.z = ((q0.z + q1.z) + q2.z) + q3.z;
            q.w = ((q0.w + q1.w) + q2.w) + q3.w;
            float4 zv = zrow[p];
            float4 st;
            st.x = zv.x + (q.x - zv.x);
            st.y = zv.y + (q.y - zv.y);
            st.z = zv.z + (q.z - zv.z);
            st.w = zv.w + (q.w - zv.w);
            rrow[p] = st;
        }
    }
    __syncthreads();   // idx reads done; h1 region may now be overwritten

    const int colg = tid & 31;   // 32 colgroups x 4 cols = 128
    const int rowg = tid >> 5;   // 16 rowgroups x 2 rows = 32
    const int c0_  = colg * 4;
    const int hr0  = rowg * 2;

    // ---- 4) h1 = relu(st @ w1 + b1) ----
    {
        float acc[2][4] = {{0.f, 0.f, 0.f, 0.f}, {0.f, 0.f, 0.f, 0.f}};
        for (int d = 0; d < DDIM; d += 4) {
            float4 a0 = *(const float4*)&resid[hr0 * DDIM + d];
            float4 a1 = *(const float4*)&resid[(hr0 + 1) * DDIM + d];
            float a0f[4] = {a0.x, a0.y, a0.z, a0.w};
            float a1f[4] = {a1.x, a1.y, a1.z, a1.w};
#pragma unroll
            for (int dd = 0; dd < 4; ++dd) {
                float4 wv = *(const float4*)&w1[(size_t)(d + dd) * NH + c0_];
                acc[0][0] = fmaf(a0f[dd], wv.x, acc[0][0]);
                acc[0][1] = fmaf(a0f[dd], wv.y, acc[0][1]);
                acc[0][2] = fmaf(a0f[dd], wv.z, acc[0][2]);
                acc[0][3] = fmaf(a0f[dd], wv.w, acc[0][3]);
                acc[1][0] = fmaf(a1f[dd], wv.x, acc[1][0]);
                acc[1][1] = fmaf(a1f[dd], wv.y, acc[1][1]);
                acc[1][2] = fmaf(a1f[dd], wv.z, acc[1][2]);
                acc[1][3] = fmaf(a1f[dd], wv.w, acc[1][3]);
            }
        }
        float4 bv = *(const float4*)&b1[c0_];
        float bf[4] = {bv.x, bv.y, bv.z, bv.w};
#pragma unroll
        for (int r = 0; r < 2; ++r) {
            float4 o;
            o.x = fmaxf(acc[r][0] + bf[0], 0.f);
            o.y = fmaxf(acc[r][1] + bf[1], 0.f);
            o.z = fmaxf(acc[r][2] + bf[2], 0.f);
            o.w = fmaxf(acc[r][3] + bf[3], 0.f);
            *(float4*)&h1[(hr0 + r) * NH + c0_] = o;
        }
    }
    __syncthreads();

    // ---- 5) h2 = relu(h1 @ w2 + b2), stored into resid region ----
    float* h2 = resid;
    {
        float acc[2][4] = {{0.f, 0.f, 0.f, 0.f}, {0.f, 0.f, 0.f, 0.f}};
        for (int d = 0; d < NH; d += 4) {
            float4 a0 = *(const float4*)&h1[hr0 * NH + d];
            float4 a1 = *(const float4*)&h1[(hr0 + 1) * NH + d];
            float a0f[4] = {a0.x, a0.y, a0.z, a0.w};
            float a1f[4] = {a1.x, a1.y, a1.z, a1.w};
#pragma unroll
            for (int dd = 0; dd < 4; ++dd) {
                float4 wv = *(const float4*)&w2[(size_t)(d + dd) * NH + c0_];
                acc[0][0] = fmaf(a0f[dd], wv.x, acc[0][0]);
                acc[0][1] = fmaf(a0f[dd], wv.y, acc[0][1]);
                acc[0][2] = fmaf(a0f[dd], wv.z, acc[0][2]);
                acc[0][3] = fmaf(a0f[dd], wv.w, acc[0][3]);
                acc[1][0] = fmaf(a1f[dd], wv.x, acc[1][0]);
                acc[1][1] = fmaf(a1f[dd], wv.y, acc[1][1]);
                acc[1][2] = fmaf(a1f[dd], wv.z, acc[1][2]);
                acc[1][3] = fmaf(a1f[dd], wv.w, acc[1][3]);
            }
        }
        float4 bv = *(const float4*)&b2[c0_];
        float bf[4] = {bv.x, bv.y, bv.z, bv.w};
        __syncthreads();   // all h1 reads done before overwriting resid
#pragma unroll
        for (int r = 0; r < 2; ++r) {
            float4 o;
            o.x = fmaxf(acc[r][0] + bf[0], 0.f);
            o.y = fmaxf(acc[r][1] + bf[1], 0.f);
            o.z = fmaxf(acc[r][2] + bf[2], 0.f);
            o.w = fmaxf(acc[r][3] + bf[3], 0.f);
            *(float4*)&h2[(hr0 + r) * NH + c0_] = o;
        }
    }
    __syncthreads();

    // ---- 6) out = h2 @ w3 + b3 ----
    if (tid < BM * NA) {
        const int r = tid / NA;
        const int a = tid - r * NA;
        const float* h2r = &h2[r * NH];
        float s = b3[a];
        for (int h = 0; h < NH; ++h)
            s = fmaf(h2r[h], w3[(size_t)h * NA + a], s);
        out[(row0 + r) * NA + a] = s;
    }
}

extern "C" void kernel_launch(void* const* d_in, const int* in_sizes, int n_in,
                              void* d_out, int out_size, void* d_ws, size_t ws_size,
                              hipStream_t stream) {
    const float* z  = (const float*)d_in[0];
    const float* cb = (const float*)d_in[1];
    const float* w1 = (const float*)d_in[2];
    const float* b1 = (const float*)d_in[3];
    const float* w2 = (const float*)d_in[4];
    const float* b2 = (const float*)d_in[5];
    const float* w3 = (const float*)d_in[6];
    const float* b3 = (const float*)d_in[7];
    float* out = (float*)d_out;
    float* halfnorm = (float*)d_ws;   // NG*NK floats = 16 KB

    (void)hipFuncSetAttribute((const void*)rvq_mlp_fused,
                              hipFuncAttributeMaxDynamicSharedMemorySize,
                              LDS_BYTES);

    rvq_norms_np<<<dim3((NG * NK + 255) / 256), dim3(256), 0, stream>>>(cb, halfnorm);
    rvq_mlp_fused<<<dim3(B_ROWS / BM), dim3(NTHREADS), LDS_BYTES, stream>>>(
        z, cb, halfnorm, w1, b1, w2, b2, w3, b3, out);
}

// Round 4
// 5513.393 us; speedup vs baseline: 3.4155x; 3.4155x over previous
//
#include <hip/hip_runtime.h>
#include <math.h>

// Problem dims (fixed by setup_inputs)
#define B_ROWS 65536
#define DDIM   512
#define NG     4
#define NK     1024
#define NH     128
#define NA     7

// Tiling
#define BM       32            // rows per block
#define NTHREADS 512           // 8 waves
#define TR       8             // rows per lane (wave rowgroup = wave&3)
#define TC       2             // consecutive codewords per lane
#define CWCHUNK  256           // codeword tile width
#define NCWC     (NK / CWCHUNK)      // 4
#define KCHUNK   64            // k tile
#define NKC      (DDIM / KCHUNK)     // 8
#define KC_SPLIT 6             // kc<6 -> accA (k<384, OpenBLAS GEMM_Q block)

// LDS layout
#define OFF_BTILE (BM * DDIM * 4)                   // 65536
#define OFF_H1    (OFF_BTILE + KCHUNK * CWCHUNK * 4) // 131072
#define OFF_REDS  (OFF_H1 + BM * NH * 4)            // 147456
#define OFF_REDI  (OFF_REDS + 2 * BM * 4)           // 147712
#define OFF_IDX   (OFF_REDI + 2 * BM * 4)           // 147968
#define LDS_BYTES (OFF_IDX + NG * BM * 4)           // 148480

// ---------------------------------------------------------------------------
// 0.5 * ||c||^2 emulating numpy fp32 np.sum(C*C, axis=-1):
// pairwise_sum, AVX512 SIMD variant (vstep=16, PW_BLOCKSIZE=128).
// fp contract OFF: each square rounds before add (C*C is a materialized array).
// ---------------------------------------------------------------------------
__global__ void rvq_norms_np(const float* __restrict__ cb,
                             float* __restrict__ halfnorm) {
#pragma clang fp contract(off)
    int k = blockIdx.x * blockDim.x + threadIdx.x;
    if (k >= NG * NK) return;
    const float* c = cb + (size_t)k * DDIM;
    float blk[4];
#pragma unroll
    for (int b = 0; b < 4; ++b) {
        const float* p = c + b * 128;
        float s[16];
#pragma unroll
        for (int l = 0; l < 16; ++l) {
            float x0 = p[l],      x1 = p[l + 16], x2 = p[l + 32], x3 = p[l + 48];
            float x4 = p[l + 64], x5 = p[l + 80], x6 = p[l + 96], x7 = p[l + 112];
            float pa = x0 * x0 + x4 * x4;
            float pb = x1 * x1 + x5 * x5;
            float pc = x2 * x2 + x6 * x6;
            float pd = x3 * x3 + x7 * x7;
            s[l] = (pa + pb) + (pc + pd);
        }
        float h[8];
#pragma unroll
        for (int l = 0; l < 8; ++l) h[l] = s[l] + s[l + 8];
        float q[4];
#pragma unroll
        for (int l = 0; l < 4; ++l) q[l] = h[l] + h[l + 4];
        float r0 = q[0] + q[2];
        float r1 = q[1] + q[3];
        blk[b] = r0 + r1;
    }
    float total = (blk[0] + blk[1]) + (blk[2] + blk[3]);
    halfnorm[k] = 0.5f * total;
}

// One k-subchunk of the bit-exact sequential fp32 FMA chain (ascending d).
#define COMPUTE_CHUNK(ACC)                                                    \
    for (int d4 = 0; d4 < KCHUNK; d4 += 4) {                                  \
        float2 bv0 = *(const float2*)&Btile[(d4 + 0) * CWCHUNK + bcol];       \
        float2 bv1 = *(const float2*)&Btile[(d4 + 1) * CWCHUNK + bcol];       \
        float2 bv2 = *(const float2*)&Btile[(d4 + 2) * CWCHUNK + bcol];       \
        float2 bv3 = *(const float2*)&Btile[(d4 + 3) * CWCHUNK + bcol];       \
        _Pragma("unroll")                                                     \
        for (int r = 0; r < TR; ++r) {                                        \
            float4 av = *(const float4*)&resid[(r0 + r) * DDIM + kb + d4];    \
            ACC[r][0] = fmaf(av.x, bv0.x, ACC[r][0]);                         \
            ACC[r][1] = fmaf(av.x, bv0.y, ACC[r][1]);                         \
            ACC[r][0] = fmaf(av.y, bv1.x, ACC[r][0]);                         \
            ACC[r][1] = fmaf(av.y, bv1.y, ACC[r][1]);                         \
            ACC[r][0] = fmaf(av.z, bv2.x, ACC[r][0]);                         \
            ACC[r][1] = fmaf(av.z, bv2.y, ACC[r][1]);                         \
            ACC[r][0] = fmaf(av.w, bv3.x, ACC[r][0]);                         \
            ACC[r][1] = fmaf(av.w, bv3.y, ACC[r][1]);                         \
        }                                                                     \
    }

// ---------------------------------------------------------------------------
// Fused: residual VQ (4 stages, np-fp32-emulated scoring, LDS-tiled GEMM) +
// reference-order quantized sum + straight-through + MLP (512->128->128->7).
// ---------------------------------------------------------------------------
__global__ __launch_bounds__(NTHREADS, 2) void rvq_mlp_fused(
    const float* __restrict__ z, const float* __restrict__ cb,
    const float* __restrict__ halfnorm,
    const float* __restrict__ w1, const float* __restrict__ b1,
    const float* __restrict__ w2, const float* __restrict__ b2,
    const float* __restrict__ w3, const float* __restrict__ b3,
    float* __restrict__ out) {
    extern __shared__ char smem[];
    float* resid = (float*)smem;                   // [BM][DDIM]
    float* Btile = (float*)(smem + OFF_BTILE);     // [KCHUNK][CWCHUNK]
    float* h1    = (float*)(smem + OFF_H1);        // [BM][NH]
    float* redS  = (float*)(smem + OFF_REDS);      // [2][BM]
    int*   redI  = (int*)(smem + OFF_REDI);        // [2][BM]
    int*   idx_s = (int*)(smem + OFF_IDX);         // [NG][BM]

    const int tid = threadIdx.x;
    const size_t row0 = (size_t)blockIdx.x * BM;

    // ---- 1) load z tile into LDS ----
    {
        const float4* src = (const float4*)(z + row0 * DDIM);
        float4* dst = (float4*)resid;
#pragma unroll
        for (int i = 0; i < (BM * DDIM / 4) / NTHREADS; ++i)
            dst[tid + i * NTHREADS] = src[tid + i * NTHREADS];
    }
    __syncthreads();

    const int cg   = tid & 63;       // lane
    const int wv   = tid >> 6;       // wave 0..7
    const int rgrp = wv & 3;         // row-group
    const int half = wv >> 1 >> 1;   // wv>>2: cw-half
    const int r0   = rgrp * TR;
    const int bcol = half * (CWCHUNK / 2) + cg * TC;

    // staging identities (2 threads per codeword row)
    const int scw   = tid >> 1;           // 0..255
    const int skoff = (tid & 1) * 32;     // 0 or 32

    // ---- 2) residual VQ stages ----
    for (int g = 0; g < NG; ++g) {
        const float* C  = cb + (size_t)g * NK * DDIM;
        const float* hn = halfnorm + g * NK;

        float sb[TR]; int ib[TR];
#pragma unroll
        for (int r = 0; r < TR; ++r) { sb[r] = -3.4e38f; ib[r] = 0; }

        for (int cwc = 0; cwc < NCWC; ++cwc) {
            const int cbase = cwc * CWCHUNK;
            float accA[TR][TC], accB[TR][TC];
#pragma unroll
            for (int r = 0; r < TR; ++r)
#pragma unroll
                for (int j = 0; j < TC; ++j) { accA[r][j] = 0.f; accB[r][j] = 0.f; }

            const float* srow = C + (size_t)(cbase + scw) * DDIM + skoff;

            // prologue: stage k-chunk 0 into regs
            float4 stv[8];
#pragma unroll
            for (int i = 0; i < 8; ++i)
                stv[i] = *(const float4*)(srow + 4 * i);

            for (int kc = 0; kc < NKC; ++kc) {
                const int kb = kc * KCHUNK;
                __syncthreads();               // previous tile consumers done
                // write staged regs -> Btile (transposed [k][cw]; 2-way bank = free)
#pragma unroll
                for (int i = 0; i < 8; ++i) {
                    const float* pv = (const float*)&stv[i];
#pragma unroll
                    for (int c = 0; c < 4; ++c)
                        Btile[(skoff + 4 * i + c) * CWCHUNK + scw] = pv[c];
                }
                __syncthreads();               // tile visible
                if (kc + 1 < NKC) {            // T14: issue next loads early
#pragma unroll
                    for (int i = 0; i < 8; ++i)
                        stv[i] = *(const float4*)(srow + (kb + KCHUNK) + 4 * i);
                }
                if (kc < KC_SPLIT) { COMPUTE_CHUNK(accA) }
                else               { COMPUTE_CHUNK(accB) }
            }

            // score = fl(S1+S2) - hn ; running argmax (cod ascending per lane)
#pragma unroll
            for (int j = 0; j < TC; ++j) {
                const int cod = cbase + bcol + j;
                const float hnv = hn[cod];
#pragma unroll
                for (int r = 0; r < TR; ++r) {
                    float s = (accA[r][j] + accB[r][j]) - hnv;
                    if (s > sb[r]) { sb[r] = s; ib[r] = cod; }
                }
            }
        }

        // ---- butterfly argmax within wave (ties -> lower index) ----
#pragma unroll
        for (int m = 32; m >= 1; m >>= 1) {
#pragma unroll
            for (int r = 0; r < TR; ++r) {
                float os = __shfl_xor(sb[r], m, 64);
                int   oi = __shfl_xor(ib[r], m, 64);
                if (os > sb[r] || (os == sb[r] && oi < ib[r])) {
                    sb[r] = os; ib[r] = oi;
                }
            }
        }
        if (cg == 0) {
#pragma unroll
            for (int r = 0; r < TR; ++r) {
                redS[half * BM + r0 + r] = sb[r];
                redI[half * BM + r0 + r] = ib[r];
            }
        }
        __syncthreads();
        // combine the two cw-halves per row
        if (tid < BM) {
            float s0 = redS[tid], s1 = redS[BM + tid];
            int   i0 = redI[tid], i1 = redI[BM + tid];
            idx_s[g * BM + tid] =
                (s1 > s0 || (s1 == s0 && i1 < i0)) ? i1 : i0;
        }
        __syncthreads();

        // ---- residual -= chosen codeword (exact fp32); skip after last ----
        if (g < NG - 1) {
            const int row = tid >> 4;
            const int sub = tid & 15;
            const float4* crow =
                (const float4*)(C + (size_t)idx_s[g * BM + row] * DDIM);
            float4* rrow = (float4*)&resid[row * DDIM];
#pragma unroll
            for (int k = 0; k < 8; ++k) {
                int p = sub + k * 16;
                float4 rv = rrow[p], cv = crow[p];
                rv.x -= cv.x; rv.y -= cv.y; rv.z -= cv.z; rv.w -= cv.w;
                rrow[p] = rv;
            }
            __syncthreads();
        }
    }

    // ---- 3) st = z + (zq - z), zq in reference order (((0+q0)+q1)+q2)+q3 ----
    {
        const int row = tid >> 4;
        const int sub = tid & 15;
        const float4* zrow = (const float4*)(z + (row0 + row) * DDIM);
        float4* rrow = (float4*)&resid[row * DDIM];
        const float4* c0 = (const float4*)(cb + ((size_t)0 * NK + idx_s[0 * BM + row]) * DDIM);
        const float4* c1 = (const float4*)(cb + ((size_t)1 * NK + idx_s[1 * BM + row]) * DDIM);
        const float4* c2 = (const float4*)(cb + ((size_t)2 * NK + idx_s[2 * BM + row]) * DDIM);
        const float4* c3 = (const float4*)(cb + ((size_t)3 * NK + idx_s[3 * BM + row]) * DDIM);
#pragma unroll
        for (int k = 0; k < 8; ++k) {
            int p = sub + k * 16;
            float4 q0 = c0[p], q1 = c1[p], q2 = c2[p], q3 = c3[p];
            float4 q;
            q.x = ((q0.x + q1.x) + q2.x) + q3.x;
            q.y = ((q0.y + q1.y) + q2.y) + q3.y;
            q.z = ((q0.z + q1.z) + q2.z) + q3.z;
            q.w = ((q0.w + q1.w) + q2.w) + q3.w;
            float4 zv = zrow[p];
            float4 st;
            st.x = zv.x + (q.x - zv.x);
            st.y = zv.y + (q.y - zv.y);
            st.z = zv.z + (q.z - zv.z);
            st.w = zv.w + (q.w - zv.w);
            rrow[p] = st;
        }
    }
    __syncthreads();

    const int colg = tid & 31;
    const int rowg = tid >> 5;
    const int c0_  = colg * 4;
    const int hr0  = rowg * 2;

    // ---- 4) h1 = relu(st @ w1 + b1) ----
    {
        float acc[2][4] = {{0.f, 0.f, 0.f, 0.f}, {0.f, 0.f, 0.f, 0.f}};
        for (int d = 0; d < DDIM; d += 4) {
            float4 a0 = *(const float4*)&resid[hr0 * DDIM + d];
            float4 a1 = *(const float4*)&resid[(hr0 + 1) * DDIM + d];
            float a0f[4] = {a0.x, a0.y, a0.z, a0.w};
            float a1f[4] = {a1.x, a1.y, a1.z, a1.w};
#pragma unroll
            for (int dd = 0; dd < 4; ++dd) {
                float4 wv2 = *(const float4*)&w1[(size_t)(d + dd) * NH + c0_];
                acc[0][0] = fmaf(a0f[dd], wv2.x, acc[0][0]);
                acc[0][1] = fmaf(a0f[dd], wv2.y, acc[0][1]);
                acc[0][2] = fmaf(a0f[dd], wv2.z, acc[0][2]);
                acc[0][3] = fmaf(a0f[dd], wv2.w, acc[0][3]);
                acc[1][0] = fmaf(a1f[dd], wv2.x, acc[1][0]);
                acc[1][1] = fmaf(a1f[dd], wv2.y, acc[1][1]);
                acc[1][2] = fmaf(a1f[dd], wv2.z, acc[1][2]);
                acc[1][3] = fmaf(a1f[dd], wv2.w, acc[1][3]);
            }
        }
        float4 bv = *(const float4*)&b1[c0_];
        float bf[4] = {bv.x, bv.y, bv.z, bv.w};
#pragma unroll
        for (int r = 0; r < 2; ++r) {
            float4 o;
            o.x = fmaxf(acc[r][0] + bf[0], 0.f);
            o.y = fmaxf(acc[r][1] + bf[1], 0.f);
            o.z = fmaxf(acc[r][2] + bf[2], 0.f);
            o.w = fmaxf(acc[r][3] + bf[3], 0.f);
            *(float4*)&h1[(hr0 + r) * NH + c0_] = o;
        }
    }
    __syncthreads();

    // ---- 5) h2 = relu(h1 @ w2 + b2), stored into resid region ----
    float* h2 = resid;
    {
        float acc[2][4] = {{0.f, 0.f, 0.f, 0.f}, {0.f, 0.f, 0.f, 0.f}};
        for (int d = 0; d < NH; d += 4) {
            float4 a0 = *(const float4*)&h1[hr0 * NH + d];
            float4 a1 = *(const float4*)&h1[(hr0 + 1) * NH + d];
            float a0f[4] = {a0.x, a0.y, a0.z, a0.w};
            float a1f[4] = {a1.x, a1.y, a1.z, a1.w};
#pragma unroll
            for (int dd = 0; dd < 4; ++dd) {
                float4 wv2 = *(const float4*)&w2[(size_t)(d + dd) * NH + c0_];
                acc[0][0] = fmaf(a0f[dd], wv2.x, acc[0][0]);
                acc[0][1] = fmaf(a0f[dd], wv2.y, acc[0][1]);
                acc[0][2] = fmaf(a0f[dd], wv2.z, acc[0][2]);
                acc[0][3] = fmaf(a0f[dd], wv2.w, acc[0][3]);
                acc[1][0] = fmaf(a1f[dd], wv2.x, acc[1][0]);
                acc[1][1] = fmaf(a1f[dd], wv2.y, acc[1][1]);
                acc[1][2] = fmaf(a1f[dd], wv2.z, acc[1][2]);
                acc[1][3] = fmaf(a1f[dd], wv2.w, acc[1][3]);
            }
        }
        float4 bv = *(const float4*)&b2[c0_];
        float bf[4] = {bv.x, bv.y, bv.z, bv.w};
        __syncthreads();
#pragma unroll
        for (int r = 0; r < 2; ++r) {
            float4 o;
            o.x = fmaxf(acc[r][0] + bf[0], 0.f);
            o.y = fmaxf(acc[r][1] + bf[1], 0.f);
            o.z = fmaxf(acc[r][2] + bf[2], 0.f);
            o.w = fmaxf(acc[r][3] + bf[3], 0.f);
            *(float4*)&h2[(hr0 + r) * NH + c0_] = o;
        }
    }
    __syncthreads();

    // ---- 6) out = h2 @ w3 + b3 ----
    if (tid < BM * NA) {
        const int r = tid / NA;
        const int a = tid - r * NA;
        const float* h2r = &h2[r * NH];
        float s = b3[a];
        for (int h = 0; h < NH; ++h)
            s = fmaf(h2r[h], w3[(size_t)h * NA + a], s);
        out[(row0 + r) * NA + a] = s;
    }
}

extern "C" void kernel_launch(void* const* d_in, const int* in_sizes, int n_in,
                              void* d_out, int out_size, void* d_ws, size_t ws_size,
                              hipStream_t stream) {
    const float* z  = (const float*)d_in[0];
    const float* cb = (const float*)d_in[1];
    const float* w1 = (const float*)d_in[2];
    const float* b1 = (const float*)d_in[3];
    const float* w2 = (const float*)d_in[4];
    const float* b2 = (const float*)d_in[5];
    const float* w3 = (const float*)d_in[6];
    const float* b3 = (const float*)d_in[7];
    float* out = (float*)d_out;
    float* halfnorm = (float*)d_ws;   // NG*NK floats = 16 KB

    (void)hipFuncSetAttribute((const void*)rvq_mlp_fused,
                              hipFuncAttributeMaxDynamicSharedMemorySize,
                              LDS_BYTES);

    rvq_norms_np<<<dim3((NG * NK + 255) / 256), dim3(256), 0, stream>>>(cb, halfnorm);
    rvq_mlp_fused<<<dim3(B_ROWS / BM), dim3(NTHREADS), LDS_BYTES, stream>>>(
        z, cb, halfnorm, w1, b1, w2, b2, w3, b3, out);
}